// Round 7
// baseline (117.823 us; speedup 1.0000x reference)
//
#include <hip/hip_runtime.h>
#include <math.h>

#define T_STEPS 256
#define BATCH   128
#define DIMD    512
#define NROWS   (T_STEPS * BATCH)   // 32768
#define PF      16                  // scan rolling-prefetch depth
#define NCHUNK  32                  // 8 timesteps per chunk
#define GEMV_BLOCKS 2048            // 16 rows per block (4 rows/wave)
#define CNT_TARGET  64              // gemv blocks per chunk
#define WRITER_BLOCKS 258
#define GRID (2 + WRITER_BLOCKS + GEMV_BLOCKS)   // 2308

#define INV2PI  0.15915494309189535f
#define L2E     1.4426950408889634f
#define TWO_L2E 2.8853900817779268f

#define AGENT __HIP_MEMORY_SCOPE_AGENT

#if __has_builtin(__builtin_amdgcn_sinf)
#define HW_SIN(x) __builtin_amdgcn_sinf(x)   // sin(2*pi*x), x in revolutions
#else
__device__ __forceinline__ float HW_SIN(float x) { return __sinf(x * 6.283185307179586f); }
#endif
#if __has_builtin(__builtin_amdgcn_exp2f)
#define EXP2(x) __builtin_amdgcn_exp2f(x)
#else
#define EXP2(x) exp2f(x)
#endif
#if __has_builtin(__builtin_amdgcn_rcpf)
#define RCP(x) __builtin_amdgcn_rcpf(x)
#else
#define RCP(x) (1.0f / (x))
#endif

// Agent-scope relaxed ops: sc-flagged, write-through/read-from coherence
// point, NO buffer_wbl2/buffer_inv (R4 lesson). Rare polls only (R5 lesson).
__device__ __forceinline__ void  st_rlx(float* p, float v) {
    __hip_atomic_store(p, v, __ATOMIC_RELAXED, AGENT);
}
__device__ __forceinline__ float ld_rlx(const float* p) {
    return __hip_atomic_load(p, __ATOMIC_RELAXED, AGENT);
}
__device__ __forceinline__ void  st_rlx_i(int* p, int v) {
    __hip_atomic_store(p, v, __ATOMIC_RELAXED, AGENT);
}
__device__ __forceinline__ int   ld_rlx_i(const int* p) {
    return __hip_atomic_load(p, __ATOMIC_RELAXED, AGENT);
}
#define VMFENCE() asm volatile("s_waitcnt vmcnt(0)" ::: "memory")
#define CFENCE()  asm volatile("" ::: "memory")

__global__ __launch_bounds__(256) void mega(
    const float* __restrict__ inp,
    const float* __restrict__ Wf, const float* __restrict__ Wi,
    const float* __restrict__ Wg, const float* __restrict__ Wo,
    const float* __restrict__ bfp, const float* __restrict__ bip,
    const float* __restrict__ bgp, const float* __restrict__ bop,
    const float* __restrict__ Pf, const float* __restrict__ Pi,
    const float* __restrict__ Pg, const float* __restrict__ Po,
    float4* __restrict__ out4,
    float4* __restrict__ X4, float* __restrict__ Hs,
    float* __restrict__ cfin, float* __restrict__ gc,
    int* __restrict__ qflag, int* __restrict__ hProg, int* __restrict__ cnt)
{
    const int bid  = blockIdx.x;
    const int tid  = threadIdx.x;
    const int wv   = tid >> 6;
    const int lane = tid & 63;

    if (bid == 0) {
        // ============== qconsts: 4 gates, one wave each ==============
        const int g = wv;
        const float* P = (g == 0) ? Pf : (g == 1) ? Pi : (g == 2) ? Pg : Po;
        const float* W = (g == 0) ? Wf : (g == 1) ? Wi : (g == 2) ? Wg : Wo;

        __shared__ float s0r[4][256], s0i[4][256], s1r[4][256], s1i[4][256];

#pragma unroll
        for (int j = 0; j < 4; ++j) {
            const int k = lane + 64 * j;
            s0r[g][k] = (k == 0)   ? 1.0f : 0.0f;  s0i[g][k] = 0.0f;
            s1r[g][k] = (k == 128) ? 1.0f : 0.0f;  s1i[g][k] = 0.0f;
        }
        __syncthreads();

        for (int l = 0; l < 2; ++l) {
            for (int w = 0; w < 8; ++w) {
                const float phi = P[l * 24 + w * 3 + 0];
                const float th  = P[l * 24 + w * 3 + 1];
                const float om  = P[l * 24 + w * 3 + 2];
                float sh, chh; __sincosf(0.5f * th, &sh, &chh);
                float sp, cp;  __sincosf(0.5f * (phi + om), &sp, &cp);
                float sm, cm;  __sincosf(0.5f * (phi - om), &sm, &cm);
                const float m00r =  cp * chh, m00i = -sp * chh;
                const float m01r = -cm * sh,  m01i = -sm * sh;
                const float m10r =  cm * sh,  m10i = -sm * sh;
                const float m11r =  cp * chh, m11i =  sp * chh;

                const int shift = 7 - w;
                const int mask  = 1 << shift;

                float n0r[4], n0i[4], n1r[4], n1i[4];
#pragma unroll
                for (int j = 0; j < 4; ++j) {
                    const int k  = lane + 64 * j;
                    const int bit = (k >> shift) & 1;
                    const int i0 = k & ~mask, i1 = k | mask;
                    const float a0r = s0r[g][i0], a0i = s0i[g][i0];
                    const float a1r = s0r[g][i1], a1i = s0i[g][i1];
                    const float b0r = s1r[g][i0], b0i = s1i[g][i0];
                    const float b1r = s1r[g][i1], b1i = s1i[g][i1];
                    const float mr0 = bit ? m10r : m00r, mi0 = bit ? m10i : m00i;
                    const float mr1 = bit ? m11r : m01r, mi1 = bit ? m11i : m01i;
                    n0r[j] = mr0 * a0r - mi0 * a0i + mr1 * a1r - mi1 * a1i;
                    n0i[j] = mr0 * a0i + mi0 * a0r + mr1 * a1i + mi1 * a1r;
                    n1r[j] = mr0 * b0r - mi0 * b0i + mr1 * b1r - mi1 * b1i;
                    n1i[j] = mr0 * b0i + mi0 * b0r + mr1 * b1i + mi1 * b1r;
                }
                __syncthreads();
#pragma unroll
                for (int j = 0; j < 4; ++j) {
                    const int k = lane + 64 * j;
                    s0r[g][k] = n0r[j]; s0i[g][k] = n0i[j];
                    s1r[g][k] = n1r[j]; s1i[g][k] = n1i[j];
                }
                __syncthreads();
            }
            float n0r[4], n0i[4], n1r[4], n1i[4];
#pragma unroll
            for (int j = 0; j < 4; ++j) {
                int src = lane + 64 * j;
                for (int w = 6; w >= 0; --w) {
                    const int cb = (src >> (7 - w)) & 1;
                    src ^= cb << (6 - w);
                }
                n0r[j] = s0r[g][src]; n0i[j] = s0i[g][src];
                n1r[j] = s1r[g][src]; n1i[j] = s1i[g][src];
            }
            __syncthreads();
#pragma unroll
            for (int j = 0; j < 4; ++j) {
                const int k = lane + 64 * j;
                s0r[g][k] = n0r[j]; s0i[g][k] = n0i[j];
                s1r[g][k] = n1r[j]; s1i[g][k] = n1i[j];
            }
            __syncthreads();
        }

        float t00 = 0, t11 = 0, t01 = 0;
#pragma unroll
        for (int j = 0; j < 4; ++j) {
            const int k = lane + 64 * j;
            const float z = (k < 128) ? 1.0f : -1.0f;
            t00 += z * (s0r[g][k] * s0r[g][k] + s0i[g][k] * s0i[g][k]);
            t11 += z * (s1r[g][k] * s1r[g][k] + s1i[g][k] * s1i[g][k]);
            t01 += z * (s0i[g][k] * s1r[g][k] - s0r[g][k] * s1i[g][k]);
        }
        float tsw = 0;
#pragma unroll
        for (int j = 0; j < 8; ++j) tsw += W[512 + lane + 64 * j];

        for (int off = 32; off; off >>= 1) {
            t00 += __shfl_xor(t00, off);
            t11 += __shfl_xor(t11, off);
            t01 += __shfl_xor(t01, off);
            tsw += __shfl_xor(tsw, off);
        }
        if (lane == 0) {
            const float A  = 0.5f * (t00 + t11);
            const float Bc = 0.5f * (t00 - t11);
            const float Bs = -t01;
            const float R  = sqrtf(Bc * Bc + Bs * Bs);
            const float ph = atan2f(Bc, Bs) * INV2PI;
            const float sc = (g == 2) ? TWO_L2E : -L2E;
            st_rlx(&gc[4 * g + 0], sc * A);
            st_rlx(&gc[4 * g + 1], sc * R);
            st_rlx(&gc[4 * g + 2], ph);
            st_rlx(&gc[4 * g + 3], tsw * INV2PI);
        }
        VMFENCE();
        __syncthreads();
        if (tid == 0) st_rlx_i(qflag, 1);
        return;
    }

    if (bid == 1) {
        // ============== scan: 128 chains, chunk-gated prefetch ==============
        if (tid >= BATCH) return;
        const int b = tid;

        while (ld_rlx_i(qflag) == 0) __builtin_amdgcn_s_sleep(2);
        CFENCE();
        float gcl[16];
#pragma unroll
        for (int j = 0; j < 16; ++j) gcl[j] = ld_rlx(&gc[j]);
        const float Af = gcl[0],  Rf = gcl[1],  phf = gcl[2],  swf = gcl[3];
        const float Ai = gcl[4],  Ri = gcl[5],  phi_ = gcl[6], swi = gcl[7];
        const float Ag = gcl[8],  Rg = gcl[9],  phg = gcl[10], swg = gcl[11];
        const float Ao = gcl[12], Ro = gcl[13], pho = gcl[14], swo = gcl[15];

        while (ld_rlx_i(&cnt[0]) < CNT_TARGET) __builtin_amdgcn_s_sleep(1);
        while (ld_rlx_i(&cnt[1]) < CNT_TARGET) __builtin_amdgcn_s_sleep(1);
        CFENCE();

        float4 p[PF];
#pragma unroll
        for (int j = 0; j < PF; ++j) p[j] = X4[j * BATCH + b];

        float c = 0.0f, h = 0.0f;
        for (int kk = 0; kk < 16; ++kk) {      // 16 steps per outer iter
            // first 8 steps: refills read chunk 2kk+2
            if (kk < 15) {
                while (ld_rlx_i(&cnt[2 * kk + 2]) < CNT_TARGET)
                    __builtin_amdgcn_s_sleep(1);
                CFENCE();
            }
#pragma unroll
            for (int j = 0; j < 8; ++j) {
                const int t = kk * 16 + j;
                const float4 xv = p[j];
                p[j] = X4[(t + PF) * BATCH + b];
                const float thf = fmaf(h, swf, xv.x + phf);
                const float thi = fmaf(h, swi, xv.y + phi_);
                const float thg = fmaf(h, swg, xv.z + phg);
                const float tho = fmaf(h, swo, xv.w + pho);
                const float Ef = fmaf(Rf, HW_SIN(thf), Af);
                const float Ei = fmaf(Ri, HW_SIN(thi), Ai);
                const float Eg = fmaf(Rg, HW_SIN(thg), Ag);
                const float Eo = fmaf(Ro, HW_SIN(tho), Ao);
                const float fg = RCP(1.0f + EXP2(Ef));
                const float ig = RCP(1.0f + EXP2(Ei));
                const float og = RCP(1.0f + EXP2(Eo));
                const float gg = 1.0f - 2.0f * RCP(EXP2(Eg) + 1.0f);
                c = fmaf(fg, c, ig * gg);
                const float y = RCP(EXP2(c * TWO_L2E) + 1.0f);
                h = fmaf(-2.0f * og, y, og);
                st_rlx(&Hs[t * BATCH + b], h);
            }
            // second 8 steps: refills read chunk 2kk+3
            if (kk < 15) {
                while (ld_rlx_i(&cnt[2 * kk + 3]) < CNT_TARGET)
                    __builtin_amdgcn_s_sleep(1);
                CFENCE();
            }
#pragma unroll
            for (int j = 8; j < 16; ++j) {
                const int t = kk * 16 + j;
                const float4 xv = p[j];
                p[j] = X4[(t + PF) * BATCH + b];
                const float thf = fmaf(h, swf, xv.x + phf);
                const float thi = fmaf(h, swi, xv.y + phi_);
                const float thg = fmaf(h, swg, xv.z + phg);
                const float tho = fmaf(h, swo, xv.w + pho);
                const float Ef = fmaf(Rf, HW_SIN(thf), Af);
                const float Ei = fmaf(Ri, HW_SIN(thi), Ai);
                const float Eg = fmaf(Rg, HW_SIN(thg), Ag);
                const float Eo = fmaf(Ro, HW_SIN(tho), Ao);
                const float fg = RCP(1.0f + EXP2(Ef));
                const float ig = RCP(1.0f + EXP2(Ei));
                const float og = RCP(1.0f + EXP2(Eo));
                const float gg = 1.0f - 2.0f * RCP(EXP2(Eg) + 1.0f);
                c = fmaf(fg, c, ig * gg);
                const float y = RCP(EXP2(c * TWO_L2E) + 1.0f);
                h = fmaf(-2.0f * og, y, og);
                st_rlx(&Hs[t * BATCH + b], h);
            }
            if (kk == 15) st_rlx(&cfin[b], c);
            if (kk & 1) {                       // publish every 32 steps
                VMFENCE();
                if (lane == 0) st_rlx_i(&hProg[wv], 16 * (kk + 1));
            }
        }
        return;
    }

    if (bid < 2 + WRITER_BLOCKS) {
        // ============== writers: t = bid-2, one quarter per wave ==============
        const int t  = bid - 2;           // 0..257 (256=hx, 257=cx)
        const int qd = wv;
        const int pidx = (qd < 2) ? 0 : 1;
        const int need = (t < 256) ? (t + 1) : 256;

        int cur = ld_rlx_i(&hProg[pidx]);
        while (cur < need) {
            int loops = ((need - cur) >> 5) + 1;   // ~1 sleep per 32 steps
            for (int s = 0; s < loops; ++s) __builtin_amdgcn_s_sleep(32);
            cur = ld_rlx_i(&hProg[pidx]);
        }
        CFENCE();

        const float* src = (t == 257) ? cfin
                         : (Hs + ((t >= 256 ? 255 : t) * BATCH));
        const float hv = src[qd * 32 + (lane & 31)];

        size_t base = (t < 256) ? ((size_t)t * 16384)
                    : (t == 256 ? (size_t)4194304 : (size_t)4210688);
        base += (size_t)qd * 4096;
#pragma unroll 8
        for (int j = 0; j < 64; ++j) {
            const float v = __shfl(hv, j >> 1);
            out4[base + j * 64 + lane] = make_float4(v, v, v, v);
        }
        return;
    }

    // ============== gemv: 4 rows per wave, weights amortized ==============
    const int gblk = bid - (2 + WRITER_BLOCKS);     // 0..2047
    const int rowbase = gblk * 16 + wv * 4;

    const float4* wfp = (const float4*)Wf;
    const float4* wip = (const float4*)Wi;
    const float4* wgp = (const float4*)Wg;
    const float4* wop = (const float4*)Wo;
    const float4 fa = wfp[lane], fb = wfp[lane + 64];
    const float4 ia = wip[lane], ib = wip[lane + 64];
    const float4 ga = wgp[lane], gb = wgp[lane + 64];
    const float4 oa = wop[lane], ob = wop[lane + 64];

    const float4* xr = (const float4*)(inp + (size_t)rowbase * DIMD);
    float sums[4][4];   // [row][gate]
#pragma unroll
    for (int r = 0; r < 4; ++r) {
        const float4 xa = xr[r * 128 + lane];
        const float4 xb = xr[r * 128 + lane + 64];
        sums[r][0] = xa.x * fa.x + xa.y * fa.y + xa.z * fa.z + xa.w * fa.w
                   + xb.x * fb.x + xb.y * fb.y + xb.z * fb.z + xb.w * fb.w;
        sums[r][1] = xa.x * ia.x + xa.y * ia.y + xa.z * ia.z + xa.w * ia.w
                   + xb.x * ib.x + xb.y * ib.y + xb.z * ib.z + xb.w * ib.w;
        sums[r][2] = xa.x * ga.x + xa.y * ga.y + xa.z * ga.z + xa.w * ga.w
                   + xb.x * gb.x + xb.y * gb.y + xb.z * gb.z + xb.w * gb.w;
        sums[r][3] = xa.x * oa.x + xa.y * oa.y + xa.z * oa.z + xa.w * oa.w
                   + xb.x * ob.x + xb.y * ob.y + xb.z * ob.z + xb.w * ob.w;
    }
#pragma unroll
    for (int r = 0; r < 4; ++r)
#pragma unroll
        for (int g = 0; g < 4; ++g)
            for (int off = 32; off; off >>= 1)
                sums[r][g] += __shfl_xor(sums[r][g], off);

    if (lane < 4) {
        const float bias = (lane == 0) ? bfp[0] : (lane == 1) ? bip[0]
                         : (lane == 2) ? bgp[0] : bop[0];
#pragma unroll
        for (int r = 0; r < 4; ++r) {
            const float s = (lane == 0) ? sums[r][0] : (lane == 1) ? sums[r][1]
                          : (lane == 2) ? sums[r][2] : sums[r][3];
            st_rlx(((float*)&X4[rowbase + r]) + lane, (s + bias) * INV2PI);
        }
    }
    VMFENCE();
    __syncthreads();
    if (tid == 0)
        __hip_atomic_fetch_add(&cnt[gblk >> 6], 1, __ATOMIC_RELAXED, AGENT);
}

extern "C" void kernel_launch(void* const* d_in, const int* in_sizes, int n_in,
                              void* d_out, int out_size, void* d_ws, size_t ws_size,
                              hipStream_t stream)
{
    const float* inp = (const float*)d_in[0];
    const float* Wf  = (const float*)d_in[1];
    const float* bfv = (const float*)d_in[2];
    const float* Pf  = (const float*)d_in[3];
    const float* Wi  = (const float*)d_in[4];
    const float* biv = (const float*)d_in[5];
    const float* Pi  = (const float*)d_in[6];
    const float* Wg  = (const float*)d_in[7];
    const float* bgv = (const float*)d_in[8];
    const float* Pg  = (const float*)d_in[9];
    const float* Wo  = (const float*)d_in[10];
    const float* bov = (const float*)d_in[11];
    const float* Po  = (const float*)d_in[12];

    float4* X4   = (float4*)d_ws;                     // NROWS + PF*BATCH
    float*  Hs   = (float*)(X4 + NROWS + PF * BATCH); // 32768
    float*  cfin = Hs + NROWS;                        // 128
    float*  gc   = cfin + BATCH;                      // 16
    int*    sync = (int*)(gc + 16);                   // qflag, hProg[2], cnt[32]
    int*    qflag = sync;
    int*    hProg = sync + 1;
    int*    cnt   = sync + 3;

    hipMemsetAsync(sync, 0, 35 * sizeof(int), stream);
    mega<<<GRID, 256, 0, stream>>>(inp, Wf, Wi, Wg, Wo,
                                   bfv, biv, bgv, bov,
                                   Pf, Pi, Pg, Po,
                                   (float4*)d_out,
                                   X4, Hs, cfin, gc, qflag, hProg, cnt);
}

// Round 8
// 57.171 us; speedup vs baseline: 2.0609x; 2.0609x over previous
//
#include <hip/hip_runtime.h>
#include <math.h>

#define T_STEPS 256
#define BATCH   128
#define DIMD    512
#define NROWS   (T_STEPS * BATCH)   // 32768
#define PF      16                  // scan rolling-prefetch depth
#define WRITER_BLOCKS 258
#define GEMV_BLOCKS 2048            // 16 rows/block, 4 rows/wave

#define INV2PI  0.15915494309189535f
#define L2E     1.4426950408889634f
#define TWO_L2E 2.8853900817779268f

#define AGENT __HIP_MEMORY_SCOPE_AGENT

#if __has_builtin(__builtin_amdgcn_sinf)
#define HW_SIN(x) __builtin_amdgcn_sinf(x)   // sin(2*pi*x), x in revolutions
#else
__device__ __forceinline__ float HW_SIN(float x) { return __sinf(x * 6.283185307179586f); }
#endif
#if __has_builtin(__builtin_amdgcn_exp2f)
#define EXP2(x) __builtin_amdgcn_exp2f(x)
#else
#define EXP2(x) exp2f(x)
#endif
#if __has_builtin(__builtin_amdgcn_rcpf)
#define RCP(x) __builtin_amdgcn_rcpf(x)
#else
#define RCP(x) (1.0f / (x))
#endif

// Agent-scope relaxed ops (sc-flagged; no wbl2/inv cache maintenance).
__device__ __forceinline__ void  st_rlx(float* p, float v) {
    __hip_atomic_store(p, v, __ATOMIC_RELAXED, AGENT);
}
__device__ __forceinline__ void  st_rlx_i(int* p, int v) {
    __hip_atomic_store(p, v, __ATOMIC_RELAXED, AGENT);
}
__device__ __forceinline__ int   ld_rlx_i(const int* p) {
    return __hip_atomic_load(p, __ATOMIC_RELAXED, AGENT);
}
#define VMFENCE() asm volatile("s_waitcnt vmcnt(0)" ::: "memory")
#define CFENCE()  asm volatile("" ::: "memory")

// ---------------------------------------------------------------------------
// prep: block 0 = qconsts (4 gates, one wave each); blocks 1.. = gemv
// (4 rows/wave). Pure producers, no cross-block sync; the dispatch
// boundary publishes gc and X4 to the next kernel.
// gc[4g+0]=scale*A, gc[4g+1]=scale*R, gc[4g+2]=phi_rev, gc[4g+3]=sumWh/2pi
// X4[t*B+b] = (dot + b0)/2pi  (phase added in the scan).
// ---------------------------------------------------------------------------
__global__ __launch_bounds__(256) void prep(
    const float* __restrict__ inp,
    const float* __restrict__ Wf, const float* __restrict__ Wi,
    const float* __restrict__ Wg, const float* __restrict__ Wo,
    const float* __restrict__ bfp, const float* __restrict__ bip,
    const float* __restrict__ bgp, const float* __restrict__ bop,
    const float* __restrict__ Pf, const float* __restrict__ Pi,
    const float* __restrict__ Pg, const float* __restrict__ Po,
    float* __restrict__ gc, int* __restrict__ hProg,
    float4* __restrict__ X4)
{
    const int bid  = blockIdx.x;
    const int wv   = threadIdx.x >> 6;
    const int lane = threadIdx.x & 63;

    if (bid == 0) {
        // ================= qconsts =================
        if (threadIdx.x == 0) { hProg[0] = 0; hProg[1] = 0; }
        const int g = wv;
        const float* P = (g == 0) ? Pf : (g == 1) ? Pi : (g == 2) ? Pg : Po;
        const float* W = (g == 0) ? Wf : (g == 1) ? Wi : (g == 2) ? Wg : Wo;

        __shared__ float s0r[4][256], s0i[4][256], s1r[4][256], s1i[4][256];

#pragma unroll
        for (int j = 0; j < 4; ++j) {
            const int k = lane + 64 * j;
            s0r[g][k] = (k == 0)   ? 1.0f : 0.0f;  s0i[g][k] = 0.0f;
            s1r[g][k] = (k == 128) ? 1.0f : 0.0f;  s1i[g][k] = 0.0f;
        }
        __syncthreads();

        for (int l = 0; l < 2; ++l) {
            for (int w = 0; w < 8; ++w) {
                const float phi = P[l * 24 + w * 3 + 0];
                const float th  = P[l * 24 + w * 3 + 1];
                const float om  = P[l * 24 + w * 3 + 2];
                float sh, chh; __sincosf(0.5f * th, &sh, &chh);
                float sp, cp;  __sincosf(0.5f * (phi + om), &sp, &cp);
                float sm, cm;  __sincosf(0.5f * (phi - om), &sm, &cm);
                const float m00r =  cp * chh, m00i = -sp * chh;
                const float m01r = -cm * sh,  m01i = -sm * sh;
                const float m10r =  cm * sh,  m10i = -sm * sh;
                const float m11r =  cp * chh, m11i =  sp * chh;

                const int shift = 7 - w;
                const int mask  = 1 << shift;

                float n0r[4], n0i[4], n1r[4], n1i[4];
#pragma unroll
                for (int j = 0; j < 4; ++j) {
                    const int k  = lane + 64 * j;
                    const int bit = (k >> shift) & 1;
                    const int i0 = k & ~mask, i1 = k | mask;
                    const float a0r = s0r[g][i0], a0i = s0i[g][i0];
                    const float a1r = s0r[g][i1], a1i = s0i[g][i1];
                    const float b0r = s1r[g][i0], b0i = s1i[g][i0];
                    const float b1r = s1r[g][i1], b1i = s1i[g][i1];
                    const float mr0 = bit ? m10r : m00r, mi0 = bit ? m10i : m00i;
                    const float mr1 = bit ? m11r : m01r, mi1 = bit ? m11i : m01i;
                    n0r[j] = mr0 * a0r - mi0 * a0i + mr1 * a1r - mi1 * a1i;
                    n0i[j] = mr0 * a0i + mi0 * a0r + mr1 * a1i + mi1 * a1r;
                    n1r[j] = mr0 * b0r - mi0 * b0i + mr1 * b1r - mi1 * b1i;
                    n1i[j] = mr0 * b0i + mi0 * b0r + mr1 * b1i + mi1 * b1r;
                }
                __syncthreads();
#pragma unroll
                for (int j = 0; j < 4; ++j) {
                    const int k = lane + 64 * j;
                    s0r[g][k] = n0r[j]; s0i[g][k] = n0i[j];
                    s1r[g][k] = n1r[j]; s1i[g][k] = n1i[j];
                }
                __syncthreads();
            }
            // CNOT chain permutation
            float n0r[4], n0i[4], n1r[4], n1i[4];
#pragma unroll
            for (int j = 0; j < 4; ++j) {
                int src = lane + 64 * j;
                for (int w = 6; w >= 0; --w) {
                    const int cb = (src >> (7 - w)) & 1;
                    src ^= cb << (6 - w);
                }
                n0r[j] = s0r[g][src]; n0i[j] = s0i[g][src];
                n1r[j] = s1r[g][src]; n1i[j] = s1i[g][src];
            }
            __syncthreads();
#pragma unroll
            for (int j = 0; j < 4; ++j) {
                const int k = lane + 64 * j;
                s0r[g][k] = n0r[j]; s0i[g][k] = n0i[j];
                s1r[g][k] = n1r[j]; s1i[g][k] = n1i[j];
            }
            __syncthreads();
        }

        float t00 = 0, t11 = 0, t01 = 0;
#pragma unroll
        for (int j = 0; j < 4; ++j) {
            const int k = lane + 64 * j;
            const float z = (k < 128) ? 1.0f : -1.0f;
            t00 += z * (s0r[g][k] * s0r[g][k] + s0i[g][k] * s0i[g][k]);
            t11 += z * (s1r[g][k] * s1r[g][k] + s1i[g][k] * s1i[g][k]);
            t01 += z * (s0i[g][k] * s1r[g][k] - s0r[g][k] * s1i[g][k]);
        }
        float tsw = 0;
#pragma unroll
        for (int j = 0; j < 8; ++j) tsw += W[512 + lane + 64 * j];

        for (int off = 32; off; off >>= 1) {
            t00 += __shfl_xor(t00, off);
            t11 += __shfl_xor(t11, off);
            t01 += __shfl_xor(t01, off);
            tsw += __shfl_xor(tsw, off);
        }
        if (lane == 0) {
            const float A  = 0.5f * (t00 + t11);
            const float Bc = 0.5f * (t00 - t11);
            const float Bs = -t01;
            const float R  = sqrtf(Bc * Bc + Bs * Bs);
            const float ph = atan2f(Bc, Bs) * INV2PI;
            const float sc = (g == 2) ? TWO_L2E : -L2E;
            gc[4 * g + 0] = sc * A;
            gc[4 * g + 1] = sc * R;
            gc[4 * g + 2] = ph;
            gc[4 * g + 3] = tsw * INV2PI;
        }
        return;
    }

    // ================= gemv: 4 rows per wave =================
    const int rowbase = (bid - 1) * 16 + wv * 4;

    const float4* wfp = (const float4*)Wf;
    const float4* wip = (const float4*)Wi;
    const float4* wgp = (const float4*)Wg;
    const float4* wop = (const float4*)Wo;
    const float4 fa = wfp[lane], fb = wfp[lane + 64];
    const float4 ia = wip[lane], ib = wip[lane + 64];
    const float4 ga = wgp[lane], gb = wgp[lane + 64];
    const float4 oa = wop[lane], ob = wop[lane + 64];

    const float4* xr = (const float4*)(inp + (size_t)rowbase * DIMD);
    float sums[4][4];   // [row][gate]
#pragma unroll
    for (int r = 0; r < 4; ++r) {
        const float4 xa = xr[r * 128 + lane];
        const float4 xb = xr[r * 128 + lane + 64];
        sums[r][0] = xa.x * fa.x + xa.y * fa.y + xa.z * fa.z + xa.w * fa.w
                   + xb.x * fb.x + xb.y * fb.y + xb.z * fb.z + xb.w * fb.w;
        sums[r][1] = xa.x * ia.x + xa.y * ia.y + xa.z * ia.z + xa.w * ia.w
                   + xb.x * ib.x + xb.y * ib.y + xb.z * ib.z + xb.w * ib.w;
        sums[r][2] = xa.x * ga.x + xa.y * ga.y + xa.z * ga.z + xa.w * ga.w
                   + xb.x * gb.x + xb.y * gb.y + xb.z * gb.z + xb.w * gb.w;
        sums[r][3] = xa.x * oa.x + xa.y * oa.y + xa.z * oa.z + xa.w * oa.w
                   + xb.x * ob.x + xb.y * ob.y + xb.z * ob.z + xb.w * ob.w;
    }
#pragma unroll
    for (int r = 0; r < 4; ++r)
#pragma unroll
        for (int g = 0; g < 4; ++g)
            for (int off = 32; off; off >>= 1)
                sums[r][g] += __shfl_xor(sums[r][g], off);

    if (lane == 0) {
        const float b0f = bfp[0], b0i = bip[0], b0g = bgp[0], b0o = bop[0];
#pragma unroll
        for (int r = 0; r < 4; ++r) {
            X4[rowbase + r] = make_float4((sums[r][0] + b0f) * INV2PI,
                                          (sums[r][1] + b0i) * INV2PI,
                                          (sums[r][2] + b0g) * INV2PI,
                                          (sums[r][3] + b0o) * INV2PI);
        }
    }
}

// ---------------------------------------------------------------------------
// Fused scan + broadcast (R6-proven). Grid 259 x 256.
// Block 0 (waves 0,1): recurrence, 64 chains each; publishes hProg[wv]
// every 32 steps. Blocks 1..258: writers (deficit-proportional sleep).
// ---------------------------------------------------------------------------
__global__ __launch_bounds__(256) void scan_write(
    const float4* __restrict__ X4, const float* __restrict__ gc,
    float* __restrict__ Hs, float* __restrict__ cfin,
    float4* __restrict__ out4, int* __restrict__ hProg)
{
    const int bid  = blockIdx.x;
    const int wv   = threadIdx.x >> 6;
    const int lane = threadIdx.x & 63;

    if (bid == 0) {
        // ---------------- scan ----------------
        if (threadIdx.x >= BATCH) return;
        const int b = threadIdx.x;

        const float Af = gc[0],  Rf = gc[1],  phf = gc[2],  swf = gc[3];
        const float Ai = gc[4],  Ri = gc[5],  phi_ = gc[6], swi = gc[7];
        const float Ag = gc[8],  Rg = gc[9],  phg = gc[10], swg = gc[11];
        const float Ao = gc[12], Ro = gc[13], pho = gc[14], swo = gc[15];

        float4 p[PF];
#pragma unroll
        for (int j = 0; j < PF; ++j) p[j] = X4[j * BATCH + b];

        float c = 0.0f, h = 0.0f;
        for (int tb = 0; tb < T_STEPS; tb += PF) {
#pragma unroll
            for (int j = 0; j < PF; ++j) {
                const int t = tb + j;
                const float4 xv = p[j];
                p[j] = X4[(t + PF) * BATCH + b];   // branchless refill (pad)

                const float thf = fmaf(h, swf, xv.x + phf);
                const float thi = fmaf(h, swi, xv.y + phi_);
                const float thg = fmaf(h, swg, xv.z + phg);
                const float tho = fmaf(h, swo, xv.w + pho);
                const float Ef = fmaf(Rf, HW_SIN(thf), Af);  // = -L2E*E
                const float Ei = fmaf(Ri, HW_SIN(thi), Ai);
                const float Eg = fmaf(Rg, HW_SIN(thg), Ag);  // = 2*L2E*E
                const float Eo = fmaf(Ro, HW_SIN(tho), Ao);
                const float fg = RCP(1.0f + EXP2(Ef));
                const float ig = RCP(1.0f + EXP2(Ei));
                const float og = RCP(1.0f + EXP2(Eo));
                const float gg = 1.0f - 2.0f * RCP(EXP2(Eg) + 1.0f);
                c = fmaf(fg, c, ig * gg);
                const float y = RCP(EXP2(c * TWO_L2E) + 1.0f);
                h = fmaf(-2.0f * og, y, og);                  // o*tanh(c)
                st_rlx(&Hs[t * BATCH + b], h);
            }
            if (tb == T_STEPS - PF) st_rlx(&cfin[b], c);
            if (((tb + PF) & 31) == 0) {       // publish every 32 steps
                VMFENCE();
                if (lane == 0) st_rlx_i(&hProg[wv], tb + PF);
            }
        }
        return;
    }

    // ---------------- writers ----------------
    const int t  = bid - 1;           // 0..257 (256=hx, 257=cx)
    const int qd = wv;                // quarter: b in [qd*32, qd*32+32)
    const int pidx = (qd < 2) ? 0 : 1;
    const int need = (t < 256) ? (t + 1) : 256;

    int cur = ld_rlx_i(&hProg[pidx]);
    while (cur < need) {
        int chunks = ((need - cur) >> 4) + 1;  // ~1 chunk-time per 16 steps
        for (int s = 0; s < chunks; ++s) __builtin_amdgcn_s_sleep(16);
        cur = ld_rlx_i(&hProg[pidx]);
    }
    CFENCE();

    const float* src = (t == 257) ? cfin : (Hs + ((t >= 256 ? 255 : t) * BATCH));
    const float hv = src[qd * 32 + (lane & 31)];

    size_t base = (t < 256) ? ((size_t)t * 16384)
                : (t == 256 ? (size_t)4194304 : (size_t)4210688);
    base += (size_t)qd * 4096;
#pragma unroll 8
    for (int j = 0; j < 64; ++j) {
        const float v = __shfl(hv, j >> 1);
        out4[base + j * 64 + lane] = make_float4(v, v, v, v);
    }
}

extern "C" void kernel_launch(void* const* d_in, const int* in_sizes, int n_in,
                              void* d_out, int out_size, void* d_ws, size_t ws_size,
                              hipStream_t stream)
{
    const float* inp = (const float*)d_in[0];
    const float* Wf  = (const float*)d_in[1];
    const float* bfv = (const float*)d_in[2];
    const float* Pf  = (const float*)d_in[3];
    const float* Wi  = (const float*)d_in[4];
    const float* biv = (const float*)d_in[5];
    const float* Pi  = (const float*)d_in[6];
    const float* Wg  = (const float*)d_in[7];
    const float* bgv = (const float*)d_in[8];
    const float* Pg  = (const float*)d_in[9];
    const float* Wo  = (const float*)d_in[10];
    const float* bov = (const float*)d_in[11];
    const float* Po  = (const float*)d_in[12];

    float4* X4   = (float4*)d_ws;                     // NROWS + PF*BATCH
    float*  Hs   = (float*)(X4 + NROWS + PF * BATCH); // 32768
    float*  cfin = Hs + NROWS;                        // 128
    float*  gc   = cfin + BATCH;                      // 16
    int*    hProg = (int*)(gc + 16);                  // 2

    prep<<<1 + GEMV_BLOCKS, 256, 0, stream>>>(inp, Wf, Wi, Wg, Wo,
                                              bfv, biv, bgv, bov,
                                              Pf, Pi, Pg, Po,
                                              gc, hProg, X4);
    scan_write<<<1 + WRITER_BLOCKS, 256, 0, stream>>>(X4, gc, Hs, cfin,
                                                      (float4*)d_out, hProg);
}

// Round 9
// 54.088 us; speedup vs baseline: 2.1784x; 1.0570x over previous
//
#include <hip/hip_runtime.h>
#include <math.h>

#define T_STEPS 256
#define BATCH   128
#define DIMD    512
#define NROWS   (T_STEPS * BATCH)   // 32768
#define PF      16                  // scan rolling-prefetch depth
#define WRITER_BLOCKS 258
#define GEMV_BLOCKS 2048            // 16 rows/block, 4 rows/wave

#define INV2PI  0.15915494309189535f
#define L2E     1.4426950408889634f
#define TWO_L2E 2.8853900817779268f

#define AGENT __HIP_MEMORY_SCOPE_AGENT

typedef float f32x4 __attribute__((ext_vector_type(4)));

#if __has_builtin(__builtin_amdgcn_sinf)
#define HW_SIN(x) __builtin_amdgcn_sinf(x)   // sin(2*pi*x), x in revolutions
#else
__device__ __forceinline__ float HW_SIN(float x) { return __sinf(x * 6.283185307179586f); }
#endif
#if __has_builtin(__builtin_amdgcn_exp2f)
#define EXP2(x) __builtin_amdgcn_exp2f(x)
#else
#define EXP2(x) exp2f(x)
#endif
#if __has_builtin(__builtin_amdgcn_rcpf)
#define RCP(x) __builtin_amdgcn_rcpf(x)
#else
#define RCP(x) (1.0f / (x))
#endif

// Agent-scope relaxed ops (sc-flagged; no wbl2/inv cache maintenance).
__device__ __forceinline__ void  st_rlx(float* p, float v) {
    __hip_atomic_store(p, v, __ATOMIC_RELAXED, AGENT);
}
__device__ __forceinline__ void  st_rlx_i(int* p, int v) {
    __hip_atomic_store(p, v, __ATOMIC_RELAXED, AGENT);
}
__device__ __forceinline__ int   ld_rlx_i(const int* p) {
    return __hip_atomic_load(p, __ATOMIC_RELAXED, AGENT);
}
#define VMFENCE() asm volatile("s_waitcnt vmcnt(0)" ::: "memory")
#define CFENCE()  asm volatile("" ::: "memory")

// ---------------------------------------------------------------------------
// prep: block 0 = qconsts (4 gates, one wave each); blocks 1.. = gemv
// (4 rows/wave). Pure producers; dispatch boundary publishes gc and X4.
// gc[4g+0]=scale*A, gc[4g+1]=scale*R, gc[4g+2]=phi_rev, gc[4g+3]=sumWh/2pi
// scale = -L2E (sigmoid f,i,o) or +2*L2E (tanh g).
// X4[t*B+b] = (dot + b0)/2pi  (phase added in the scan at refill time).
// ---------------------------------------------------------------------------
__global__ __launch_bounds__(256) void prep(
    const float* __restrict__ inp,
    const float* __restrict__ Wf, const float* __restrict__ Wi,
    const float* __restrict__ Wg, const float* __restrict__ Wo,
    const float* __restrict__ bfp, const float* __restrict__ bip,
    const float* __restrict__ bgp, const float* __restrict__ bop,
    const float* __restrict__ Pf, const float* __restrict__ Pi,
    const float* __restrict__ Pg, const float* __restrict__ Po,
    float* __restrict__ gc, int* __restrict__ hProg,
    float4* __restrict__ X4)
{
    const int bid  = blockIdx.x;
    const int wv   = threadIdx.x >> 6;
    const int lane = threadIdx.x & 63;

    if (bid == 0) {
        // ================= qconsts =================
        if (threadIdx.x == 0) { hProg[0] = 0; hProg[1] = 0; }
        const int g = wv;
        const float* P = (g == 0) ? Pf : (g == 1) ? Pi : (g == 2) ? Pg : Po;
        const float* W = (g == 0) ? Wf : (g == 1) ? Wi : (g == 2) ? Wg : Wo;

        __shared__ float s0r[4][256], s0i[4][256], s1r[4][256], s1i[4][256];

#pragma unroll
        for (int j = 0; j < 4; ++j) {
            const int k = lane + 64 * j;
            s0r[g][k] = (k == 0)   ? 1.0f : 0.0f;  s0i[g][k] = 0.0f;
            s1r[g][k] = (k == 128) ? 1.0f : 0.0f;  s1i[g][k] = 0.0f;
        }
        __syncthreads();

        for (int l = 0; l < 2; ++l) {
            for (int w = 0; w < 8; ++w) {
                const float phi = P[l * 24 + w * 3 + 0];
                const float th  = P[l * 24 + w * 3 + 1];
                const float om  = P[l * 24 + w * 3 + 2];
                float sh, chh; __sincosf(0.5f * th, &sh, &chh);
                float sp, cp;  __sincosf(0.5f * (phi + om), &sp, &cp);
                float sm, cm;  __sincosf(0.5f * (phi - om), &sm, &cm);
                const float m00r =  cp * chh, m00i = -sp * chh;
                const float m01r = -cm * sh,  m01i = -sm * sh;
                const float m10r =  cm * sh,  m10i = -sm * sh;
                const float m11r =  cp * chh, m11i =  sp * chh;

                const int shift = 7 - w;
                const int mask  = 1 << shift;

                float n0r[4], n0i[4], n1r[4], n1i[4];
#pragma unroll
                for (int j = 0; j < 4; ++j) {
                    const int k  = lane + 64 * j;
                    const int bit = (k >> shift) & 1;
                    const int i0 = k & ~mask, i1 = k | mask;
                    const float a0r = s0r[g][i0], a0i = s0i[g][i0];
                    const float a1r = s0r[g][i1], a1i = s0i[g][i1];
                    const float b0r = s1r[g][i0], b0i = s1i[g][i0];
                    const float b1r = s1r[g][i1], b1i = s1i[g][i1];
                    const float mr0 = bit ? m10r : m00r, mi0 = bit ? m10i : m00i;
                    const float mr1 = bit ? m11r : m01r, mi1 = bit ? m11i : m01i;
                    n0r[j] = mr0 * a0r - mi0 * a0i + mr1 * a1r - mi1 * a1i;
                    n0i[j] = mr0 * a0i + mi0 * a0r + mr1 * a1i + mi1 * a1r;
                    n1r[j] = mr0 * b0r - mi0 * b0i + mr1 * b1r - mi1 * b1i;
                    n1i[j] = mr0 * b0i + mi0 * b0r + mr1 * b1i + mi1 * b1r;
                }
                __syncthreads();
#pragma unroll
                for (int j = 0; j < 4; ++j) {
                    const int k = lane + 64 * j;
                    s0r[g][k] = n0r[j]; s0i[g][k] = n0i[j];
                    s1r[g][k] = n1r[j]; s1i[g][k] = n1i[j];
                }
                __syncthreads();
            }
            // CNOT chain permutation
            float n0r[4], n0i[4], n1r[4], n1i[4];
#pragma unroll
            for (int j = 0; j < 4; ++j) {
                int src = lane + 64 * j;
                for (int w = 6; w >= 0; --w) {
                    const int cb = (src >> (7 - w)) & 1;
                    src ^= cb << (6 - w);
                }
                n0r[j] = s0r[g][src]; n0i[j] = s0i[g][src];
                n1r[j] = s1r[g][src]; n1i[j] = s1i[g][src];
            }
            __syncthreads();
#pragma unroll
            for (int j = 0; j < 4; ++j) {
                const int k = lane + 64 * j;
                s0r[g][k] = n0r[j]; s0i[g][k] = n0i[j];
                s1r[g][k] = n1r[j]; s1i[g][k] = n1i[j];
            }
            __syncthreads();
        }

        float t00 = 0, t11 = 0, t01 = 0;
#pragma unroll
        for (int j = 0; j < 4; ++j) {
            const int k = lane + 64 * j;
            const float z = (k < 128) ? 1.0f : -1.0f;
            t00 += z * (s0r[g][k] * s0r[g][k] + s0i[g][k] * s0i[g][k]);
            t11 += z * (s1r[g][k] * s1r[g][k] + s1i[g][k] * s1i[g][k]);
            t01 += z * (s0i[g][k] * s1r[g][k] - s0r[g][k] * s1i[g][k]);
        }
        float tsw = 0;
#pragma unroll
        for (int j = 0; j < 8; ++j) tsw += W[512 + lane + 64 * j];

        for (int off = 32; off; off >>= 1) {
            t00 += __shfl_xor(t00, off);
            t11 += __shfl_xor(t11, off);
            t01 += __shfl_xor(t01, off);
            tsw += __shfl_xor(tsw, off);
        }
        if (lane == 0) {
            const float A  = 0.5f * (t00 + t11);
            const float Bc = 0.5f * (t00 - t11);
            const float Bs = -t01;
            const float R  = sqrtf(Bc * Bc + Bs * Bs);
            const float ph = atan2f(Bc, Bs) * INV2PI;
            const float sc = (g == 2) ? TWO_L2E : -L2E;
            gc[4 * g + 0] = sc * A;
            gc[4 * g + 1] = sc * R;
            gc[4 * g + 2] = ph;
            gc[4 * g + 3] = tsw * INV2PI;
        }
        return;
    }

    // ================= gemv: 4 rows per wave =================
    const int rowbase = (bid - 1) * 16 + wv * 4;

    const float4* wfp = (const float4*)Wf;
    const float4* wip = (const float4*)Wi;
    const float4* wgp = (const float4*)Wg;
    const float4* wop = (const float4*)Wo;
    const float4 fa = wfp[lane], fb = wfp[lane + 64];
    const float4 ia = wip[lane], ib = wip[lane + 64];
    const float4 ga = wgp[lane], gb = wgp[lane + 64];
    const float4 oa = wop[lane], ob = wop[lane + 64];

    const float4* xr = (const float4*)(inp + (size_t)rowbase * DIMD);
    float sums[4][4];   // [row][gate]
#pragma unroll
    for (int r = 0; r < 4; ++r) {
        const float4 xa = xr[r * 128 + lane];
        const float4 xb = xr[r * 128 + lane + 64];
        sums[r][0] = xa.x * fa.x + xa.y * fa.y + xa.z * fa.z + xa.w * fa.w
                   + xb.x * fb.x + xb.y * fb.y + xb.z * fb.z + xb.w * fb.w;
        sums[r][1] = xa.x * ia.x + xa.y * ia.y + xa.z * ia.z + xa.w * ia.w
                   + xb.x * ib.x + xb.y * ib.y + xb.z * ib.z + xb.w * ib.w;
        sums[r][2] = xa.x * ga.x + xa.y * ga.y + xa.z * ga.z + xa.w * ga.w
                   + xb.x * gb.x + xb.y * gb.y + xb.z * gb.z + xb.w * gb.w;
        sums[r][3] = xa.x * oa.x + xa.y * oa.y + xa.z * oa.z + xa.w * oa.w
                   + xb.x * ob.x + xb.y * ob.y + xb.z * ob.z + xb.w * ob.w;
    }
#pragma unroll
    for (int r = 0; r < 4; ++r)
#pragma unroll
        for (int g = 0; g < 4; ++g)
            for (int off = 32; off; off >>= 1)
                sums[r][g] += __shfl_xor(sums[r][g], off);

    if (lane == 0) {
        const float b0f = bfp[0], b0i = bip[0], b0g = bgp[0], b0o = bop[0];
#pragma unroll
        for (int r = 0; r < 4; ++r) {
            X4[rowbase + r] = make_float4((sums[r][0] + b0f) * INV2PI,
                                          (sums[r][1] + b0i) * INV2PI,
                                          (sums[r][2] + b0g) * INV2PI,
                                          (sums[r][3] + b0o) * INV2PI);
        }
    }
}

// ---------------------------------------------------------------------------
// Fused scan + broadcast. Grid 259 x 256.
// Block 0 (waves 0,1): recurrence, 64 chains each, merged-rcp math
// (11 transcendentals/step); publishes hProg[wv] every 32 steps.
// Blocks 1..258: writers (deficit-proportional sleep, NT output stores).
// ---------------------------------------------------------------------------
__global__ __launch_bounds__(256) void scan_write(
    const float4* __restrict__ X4, const float* __restrict__ gc,
    float* __restrict__ Hs, float* __restrict__ cfin,
    float4* __restrict__ out4, int* __restrict__ hProg)
{
    const int bid  = blockIdx.x;
    const int wv   = threadIdx.x >> 6;
    const int lane = threadIdx.x & 63;

    if (bid == 0) {
        // ---------------- scan ----------------
        if (threadIdx.x >= BATCH) return;
        const int b = threadIdx.x;

        const float Af = gc[0],  Rf = gc[1],  phf = gc[2],  swf = gc[3];
        const float Ai = gc[4],  Ri = gc[5],  phi_ = gc[6], swi = gc[7];
        const float Ag = gc[8],  Rg = gc[9],  phg = gc[10], swg = gc[11];
        const float Ao = gc[12], Ro = gc[13], pho = gc[14], swo = gc[15];

        float4 p[PF];
#pragma unroll
        for (int j = 0; j < PF; ++j) {
            const float4 v = X4[j * BATCH + b];
            p[j] = make_float4(v.x + phf, v.y + phi_, v.z + phg, v.w + pho);
        }

        float c = 0.0f, h = 0.0f;
        for (int tb = 0; tb < T_STEPS; tb += PF) {
#pragma unroll
            for (int j = 0; j < PF; ++j) {
                const int t = tb + j;
                const float4 xv = p[j];
                {   // branchless refill PF ahead; fold phases off-chain
                    const float4 v = X4[(t + PF) * BATCH + b];
                    p[j] = make_float4(v.x + phf, v.y + phi_,
                                       v.z + phg, v.w + pho);
                }
                const float thf = fmaf(h, swf, xv.x);
                const float thi = fmaf(h, swi, xv.y);
                const float thg = fmaf(h, swg, xv.z);
                const float tho = fmaf(h, swo, xv.w);
                // e = exp(-E_raw) for f,i,o ; exp(+2 E_raw) for g
                const float ef = EXP2(fmaf(Rf, HW_SIN(thf), Af));
                const float ei = EXP2(fmaf(Ri, HW_SIN(thi), Ai));
                const float eg = EXP2(fmaf(Rg, HW_SIN(thg), Ag));
                const float eo = EXP2(fmaf(Ro, HW_SIN(tho), Ao));
                const float Ff = ef + 1.0f, Fi = ei + 1.0f;
                const float Fg = eg + 1.0f, Fo = eo + 1.0f;
                // c' = fg*c + ig*gg  (single rcp)
                const float FiFg = Fi * Fg;
                const float num  = fmaf(c, FiFg, (eg - 1.0f) * Ff);
                c = num * RCP(Ff * FiFg);
                // h = og * tanh(c)  (single rcp)
                const float ec = EXP2(c * TWO_L2E);
                h = (ec - 1.0f) * RCP(Fo * (ec + 1.0f));
                st_rlx(&Hs[t * BATCH + b], h);
            }
            if (tb == T_STEPS - PF) st_rlx(&cfin[b], c);
            if (((tb + PF) & 31) == 0) {       // publish every 32 steps
                VMFENCE();
                if (lane == 0) st_rlx_i(&hProg[wv], tb + PF);
            }
        }
        return;
    }

    // ---------------- writers ----------------
    const int t  = bid - 1;           // 0..257 (256=hx, 257=cx)
    const int qd = wv;                // quarter: b in [qd*32, qd*32+32)
    const int pidx = (qd < 2) ? 0 : 1;
    const int need = (t < 256) ? (t + 1) : 256;

    int cur = ld_rlx_i(&hProg[pidx]);
    while (cur < need) {
        int chunks = ((need - cur) >> 4) + 1;  // ~1 chunk-time per 16 steps
        for (int s = 0; s < chunks; ++s) __builtin_amdgcn_s_sleep(16);
        cur = ld_rlx_i(&hProg[pidx]);
    }
    CFENCE();

    const float* src = (t == 257) ? cfin : (Hs + ((t >= 256 ? 255 : t) * BATCH));
    const float hv = src[qd * 32 + (lane & 31)];

    size_t base = (t < 256) ? ((size_t)t * 16384)
                : (t == 256 ? (size_t)4194304 : (size_t)4210688);
    base += (size_t)qd * 4096;
#pragma unroll 8
    for (int j = 0; j < 64; ++j) {
        const float v = __shfl(hv, j >> 1);
        const f32x4 val = {v, v, v, v};
        __builtin_nontemporal_store(val, (f32x4*)(out4 + base + j * 64 + lane));
    }
}

extern "C" void kernel_launch(void* const* d_in, const int* in_sizes, int n_in,
                              void* d_out, int out_size, void* d_ws, size_t ws_size,
                              hipStream_t stream)
{
    const float* inp = (const float*)d_in[0];
    const float* Wf  = (const float*)d_in[1];
    const float* bfv = (const float*)d_in[2];
    const float* Pf  = (const float*)d_in[3];
    const float* Wi  = (const float*)d_in[4];
    const float* biv = (const float*)d_in[5];
    const float* Pi  = (const float*)d_in[6];
    const float* Wg  = (const float*)d_in[7];
    const float* bgv = (const float*)d_in[8];
    const float* Pg  = (const float*)d_in[9];
    const float* Wo  = (const float*)d_in[10];
    const float* bov = (const float*)d_in[11];
    const float* Po  = (const float*)d_in[12];

    float4* X4   = (float4*)d_ws;                     // NROWS + PF*BATCH
    float*  Hs   = (float*)(X4 + NROWS + PF * BATCH); // 32768
    float*  cfin = Hs + NROWS;                        // 128
    float*  gc   = cfin + BATCH;                      // 16
    int*    hProg = (int*)(gc + 16);                  // 2

    prep<<<1 + GEMV_BLOCKS, 256, 0, stream>>>(inp, Wf, Wi, Wg, Wo,
                                              bfv, biv, bgv, bov,
                                              Pf, Pi, Pg, Po,
                                              gc, hProg, X4);
    scan_write<<<1 + WRITER_BLOCKS, 256, 0, stream>>>(X4, gc, Hs, cfin,
                                                      (float4*)d_out, hProg);
}